// Round 12
// baseline (419.873 us; speedup 1.0000x reference)
//
#include <hip/hip_runtime.h>

#define NN 40000
#define NE 640000
#define HID 128
#define SCAN_BLK ((NN + 255) / 256)   // 157

typedef __attribute__((ext_vector_type(8)))  short short8;
typedef __attribute__((ext_vector_type(4)))  short short4v;
typedef __attribute__((ext_vector_type(16))) float floatx16;
typedef unsigned int uint;

__device__ __forceinline__ short f2bf(float f) {
    union { float f; unsigned u; } c; c.f = f;
    unsigned u = c.u;
    unsigned r = (u + 0x7FFF + ((u >> 16) & 1)) >> 16;   // RNE
    return (short)r;
}
__device__ __forceinline__ float bf2f(short h) {
    union { unsigned u; float f; } c;
    c.u = ((unsigned)(unsigned short)h) << 16;
    return c.f;
}
__device__ __forceinline__ float asf(uint u) {
    union { uint u; float f; } c; c.u = u; return c.f;
}
// Packed split-bf16: u32 = (hi_bf16 << 16) | lo_bf16; hi+lo ~ x to ~2^-17 rel.
__device__ __forceinline__ uint packsplit(float f) {
    short h = f2bf(f);
    short l = f2bf(f - bf2f(h));
    return ((uint)(unsigned short)h << 16) | (uint)(unsigned short)l;
}
__device__ __forceinline__ float unpackf(uint u) {
    return asf(u & 0xFFFF0000u) + asf(u << 16);
}
__device__ __forceinline__ void unpack8(uint4 a, uint4 b, short8* h, short8* l) {
    short8 H, L;
    H[0] = (short)(a.x >> 16); L[0] = (short)a.x;
    H[1] = (short)(a.y >> 16); L[1] = (short)a.y;
    H[2] = (short)(a.z >> 16); L[2] = (short)a.z;
    H[3] = (short)(a.w >> 16); L[3] = (short)a.w;
    H[4] = (short)(b.x >> 16); L[4] = (short)b.x;
    H[5] = (short)(b.y >> 16); L[5] = (short)b.y;
    H[6] = (short)(b.z >> 16); L[6] = (short)b.z;
    H[7] = (short)(b.w >> 16); L[7] = (short)b.w;
    *h = H; *l = L;
}

// W fragment swizzle (HW-verified r9-r11): element (o,k) of [128][WS] row-major
// -> index so a wave's B-load is base + lane*8 uints (coalesced).
__device__ __forceinline__ int wswz(int o, int k) {
    int chunk = k >> 4, half = (k >> 3) & 1, j = k & 7;
    int ct = o >> 5, m31 = o & 31;
    int lane = half * 32 + m31;
    return (((chunk * 4 + ct) * 64 + lane) * 8 + j);
}

// ---------------- fused gather + split-bf16 MFMA linear (512 thr, 8 waves) --
// out[n][:] = relu( W · (sum_{e: dst=n} h[src[e]]) + b ), 32 nodes per block.
// Gather: 2 passes x 16 nodes (2x outstanding loads vs r11's 4x8).
// GEMM: waves 0-3 only (3 us; co-resident blocks' gathers cover the idle).
// 40 VGPR + 16 KB LDS -> 4 blocks/CU = 32 waves/CU (full capacity).
__global__ __launch_bounds__(512, 4) void fused_gather_lin_kernel(
    const uint* __restrict__ h, const int* __restrict__ row_ptr,
    const int* __restrict__ esrc, const uint* __restrict__ Wq,
    const float* __restrict__ bias, uint* __restrict__ out)
{
    __shared__ short sAh[4096];
    __shared__ short sAl[4096];
    const int t  = threadIdx.x;
    const int r0 = blockIdx.x * 32;
    const int c4 = t & 31;
    const int sub = c4 >> 1;
    const int j0  = (c4 & 1) * 4;

    #pragma unroll
    for (int p = 0; p < 2; ++p) {
        const int nl   = p * 16 + (t >> 5);
        const int node = r0 + nl;
        const int lo = row_ptr[node], hi = row_ptr[node + 1];
        float4 aH = make_float4(0,0,0,0), aL = make_float4(0,0,0,0);
        float4 bH = make_float4(0,0,0,0), bL = make_float4(0,0,0,0);
        float4 cH = make_float4(0,0,0,0), cL = make_float4(0,0,0,0);
        float4 dH = make_float4(0,0,0,0), dL = make_float4(0,0,0,0);
        int e = lo;
        for (; e + 4 <= hi; e += 4) {
            int s0 = esrc[e], s1 = esrc[e+1], s2 = esrc[e+2], s3 = esrc[e+3];
            uint4 u0 = *(const uint4*)(h + (size_t)s0 * HID + c4 * 4);
            uint4 u1 = *(const uint4*)(h + (size_t)s1 * HID + c4 * 4);
            uint4 u2 = *(const uint4*)(h + (size_t)s2 * HID + c4 * 4);
            uint4 u3 = *(const uint4*)(h + (size_t)s3 * HID + c4 * 4);
            aH.x += asf(u0.x & 0xFFFF0000u); aL.x += asf(u0.x << 16);
            aH.y += asf(u0.y & 0xFFFF0000u); aL.y += asf(u0.y << 16);
            aH.z += asf(u0.z & 0xFFFF0000u); aL.z += asf(u0.z << 16);
            aH.w += asf(u0.w & 0xFFFF0000u); aL.w += asf(u0.w << 16);
            bH.x += asf(u1.x & 0xFFFF0000u); bL.x += asf(u1.x << 16);
            bH.y += asf(u1.y & 0xFFFF0000u); bL.y += asf(u1.y << 16);
            bH.z += asf(u1.z & 0xFFFF0000u); bL.z += asf(u1.z << 16);
            bH.w += asf(u1.w & 0xFFFF0000u); bL.w += asf(u1.w << 16);
            cH.x += asf(u2.x & 0xFFFF0000u); cL.x += asf(u2.x << 16);
            cH.y += asf(u2.y & 0xFFFF0000u); cL.y += asf(u2.y << 16);
            cH.z += asf(u2.z & 0xFFFF0000u); cL.z += asf(u2.z << 16);
            cH.w += asf(u2.w & 0xFFFF0000u); cL.w += asf(u2.w << 16);
            dH.x += asf(u3.x & 0xFFFF0000u); dL.x += asf(u3.x << 16);
            dH.y += asf(u3.y & 0xFFFF0000u); dL.y += asf(u3.y << 16);
            dH.z += asf(u3.z & 0xFFFF0000u); dL.z += asf(u3.z << 16);
            dH.w += asf(u3.w & 0xFFFF0000u); dL.w += asf(u3.w << 16);
        }
        for (; e < hi; ++e) {
            int s0 = esrc[e];
            uint4 u0 = *(const uint4*)(h + (size_t)s0 * HID + c4 * 4);
            aH.x += asf(u0.x & 0xFFFF0000u); aL.x += asf(u0.x << 16);
            aH.y += asf(u0.y & 0xFFFF0000u); aL.y += asf(u0.y << 16);
            aH.z += asf(u0.z & 0xFFFF0000u); aL.z += asf(u0.z << 16);
            aH.w += asf(u0.w & 0xFFFF0000u); aL.w += asf(u0.w << 16);
        }
        float vx = (aH.x + bH.x) + (cH.x + dH.x) + (aL.x + bL.x) + (cL.x + dL.x);
        float vy = (aH.y + bH.y) + (cH.y + dH.y) + (aL.y + bL.y) + (cL.y + dL.y);
        float vz = (aH.z + bH.z) + (cH.z + dH.z) + (aL.z + bL.z) + (cL.z + dL.z);
        float vw = (aH.w + bH.w) + (cH.w + dH.w) + (aL.w + bL.w) + (cL.w + dL.w);
        short4v Hq, Lq;
        short hh;
        hh = f2bf(vx); Hq.x = hh; Lq.x = f2bf(vx - bf2f(hh));
        hh = f2bf(vy); Hq.y = hh; Lq.y = f2bf(vy - bf2f(hh));
        hh = f2bf(vz); Hq.z = hh; Lq.z = f2bf(vz - bf2f(hh));
        hh = f2bf(vw); Hq.w = hh; Lq.w = f2bf(vw - bf2f(hh));
        const int off = sub * 256 + nl * 8 + j0;
        *(short4v*)(sAh + off) = Hq;
        *(short4v*)(sAl + off) = Lq;
    }
    __syncthreads();

    const int wv = t >> 6;
    if (wv < 4) {
        const int lane = t & 63;
        const int m31  = lane & 31;
        const int half = lane >> 5;
        floatx16 acc;
        #pragma unroll
        for (int i = 0; i < 16; ++i) acc[i] = 0.f;
        #pragma unroll
        for (int c = 0; c < 8; ++c) {
            short8 ah = *(const short8*)(sAh + (c * 2 + half) * 256 + m31 * 8);
            short8 al = *(const short8*)(sAl + (c * 2 + half) * 256 + m31 * 8);
            const uint* wr = Wq + ((size_t)(c * 4 + wv) * 64 + lane) * 8;
            uint4 w0 = *(const uint4*)(wr);
            uint4 w1 = *(const uint4*)(wr + 4);
            short8 bh, bl;
            unpack8(w0, w1, &bh, &bl);
            acc = __builtin_amdgcn_mfma_f32_32x32x16_bf16(ah, bh, acc, 0, 0, 0);
            acc = __builtin_amdgcn_mfma_f32_32x32x16_bf16(al, bh, acc, 0, 0, 0);
            acc = __builtin_amdgcn_mfma_f32_32x32x16_bf16(ah, bl, acc, 0, 0, 0);
        }
        const int col = wv * 32 + m31;
        const float bb = bias[col];
        #pragma unroll
        for (int reg = 0; reg < 16; ++reg) {
            int row = (reg & 3) + 8 * (reg >> 2) + 4 * half;
            float v = fmaxf(acc[reg] + bb, 0.f);
            out[(size_t)(r0 + row) * HID + col] = packsplit(v);
        }
    }
}

// ---------------- standalone split-bf16 MFMA linear, 32-row tiles ----------
template<int PHASES, bool RELU>
__global__ __launch_bounds__(256, 4) void lin32_kernel(
    const uint* __restrict__ X0, const uint* __restrict__ X1,
    const uint* __restrict__ Wq, const float* __restrict__ bias,
    uint* __restrict__ out)
{
    __shared__ short sAh[PHASES * 4096];
    __shared__ short sAl[PHASES * 4096];
    const int t  = threadIdx.x;
    const int r0 = blockIdx.x * 32;

    #pragma unroll
    for (int i = 0; i < PHASES * 4; ++i) {
        int v = t + 256 * i;
        const uint* Xp = (PHASES == 2 && v >= 1024) ? X1 : X0;
        int vv  = v & 1023;
        int row = vv >> 5, q = vv & 31;
        uint4 u = *(const uint4*)(Xp + (size_t)(r0 + row) * 128 + q * 4);
        int kk  = ((PHASES == 2) ? (v >> 10) * 128 : 0) + q * 4;
        int off = (kk >> 3) * 256 + row * 8 + (q & 1) * 4;
        short4v hi, lo;
        hi.x = (short)(u.x >> 16); lo.x = (short)u.x;
        hi.y = (short)(u.y >> 16); lo.y = (short)u.y;
        hi.z = (short)(u.z >> 16); lo.z = (short)u.z;
        hi.w = (short)(u.w >> 16); lo.w = (short)u.w;
        *(short4v*)(sAh + off) = hi;
        *(short4v*)(sAl + off) = lo;
    }
    __syncthreads();

    const int wv   = t >> 6;
    const int lane = t & 63;
    const int m31  = lane & 31;
    const int half = lane >> 5;
    floatx16 acc;
    #pragma unroll
    for (int i = 0; i < 16; ++i) acc[i] = 0.f;
    #pragma unroll
    for (int c = 0; c < PHASES * 8; ++c) {
        short8 ah = *(const short8*)(sAh + (c * 2 + half) * 256 + m31 * 8);
        short8 al = *(const short8*)(sAl + (c * 2 + half) * 256 + m31 * 8);
        const uint* wr = Wq + ((size_t)(c * 4 + wv) * 64 + lane) * 8;
        uint4 w0 = *(const uint4*)(wr);
        uint4 w1 = *(const uint4*)(wr + 4);
        short8 bh, bl;
        unpack8(w0, w1, &bh, &bl);
        acc = __builtin_amdgcn_mfma_f32_32x32x16_bf16(ah, bh, acc, 0, 0, 0);
        acc = __builtin_amdgcn_mfma_f32_32x32x16_bf16(al, bh, acc, 0, 0, 0);
        acc = __builtin_amdgcn_mfma_f32_32x32x16_bf16(ah, bl, acc, 0, 0, 0);
    }
    const int col = wv * 32 + m31;
    const float bb = bias[col];
    #pragma unroll
    for (int reg = 0; reg < 16; ++reg) {
        int row = (reg & 3) + 8 * (reg >> 2) + 4 * half;
        float v = acc[reg] + bb;
        if (RELU) v = fmaxf(v, 0.f);
        out[(size_t)(r0 + row) * HID + col] = packsplit(v);
    }
}

// ---------------- cat-GEMM (Wb) + fused head ------------------------------
__global__ __launch_bounds__(256, 3) void cat_head_kernel(
    const uint* __restrict__ X0, const uint* __restrict__ X1,
    const uint* __restrict__ Wq, const float* __restrict__ bias,
    const float* __restrict__ f2, const float* __restrict__ f2b,
    float* __restrict__ out)
{
    __shared__ short sAh[8192];
    __shared__ short sAl[8192];
    __shared__ float gbuf[32 * 129];
    const int t  = threadIdx.x;
    const int r0 = blockIdx.x * 32;

    #pragma unroll
    for (int i = 0; i < 8; ++i) {
        int v = t + 256 * i;
        const uint* Xp = (v >= 1024) ? X1 : X0;
        int vv  = v & 1023;
        int row = vv >> 5, q = vv & 31;
        uint4 u = *(const uint4*)(Xp + (size_t)(r0 + row) * 128 + q * 4);
        int kk  = (v >> 10) * 128 + q * 4;
        int off = (kk >> 3) * 256 + row * 8 + (q & 1) * 4;
        short4v hi, lo;
        hi.x = (short)(u.x >> 16); lo.x = (short)u.x;
        hi.y = (short)(u.y >> 16); lo.y = (short)u.y;
        hi.z = (short)(u.z >> 16); lo.z = (short)u.z;
        hi.w = (short)(u.w >> 16); lo.w = (short)u.w;
        *(short4v*)(sAh + off) = hi;
        *(short4v*)(sAl + off) = lo;
    }
    __syncthreads();

    const int wv   = t >> 6;
    const int lane = t & 63;
    const int m31  = lane & 31;
    const int half = lane >> 5;
    floatx16 acc;
    #pragma unroll
    for (int i = 0; i < 16; ++i) acc[i] = 0.f;
    #pragma unroll
    for (int c = 0; c < 16; ++c) {
        short8 ah = *(const short8*)(sAh + (c * 2 + half) * 256 + m31 * 8);
        short8 al = *(const short8*)(sAl + (c * 2 + half) * 256 + m31 * 8);
        const uint* wr = Wq + ((size_t)(c * 4 + wv) * 64 + lane) * 8;
        uint4 w0 = *(const uint4*)(wr);
        uint4 w1 = *(const uint4*)(wr + 4);
        short8 bh, bl;
        unpack8(w0, w1, &bh, &bl);
        acc = __builtin_amdgcn_mfma_f32_32x32x16_bf16(ah, bh, acc, 0, 0, 0);
        acc = __builtin_amdgcn_mfma_f32_32x32x16_bf16(al, bh, acc, 0, 0, 0);
        acc = __builtin_amdgcn_mfma_f32_32x32x16_bf16(ah, bl, acc, 0, 0, 0);
    }
    const int col = wv * 32 + m31;
    const float bb = bias[col];
    #pragma unroll
    for (int reg = 0; reg < 16; ++reg) {
        int row = (reg & 3) + 8 * (reg >> 2) + 4 * half;
        gbuf[row * 129 + col] = fmaxf(acc[reg] + bb, 0.f);
    }
    __syncthreads();

    const int node = t >> 3;
    const int seg  = t & 7;
    const float* gr = gbuf + node * 129 + seg * 16;
    float a = 0.f;
    #pragma unroll
    for (int i = 0; i < 16; ++i) a += gr[i] * f2[seg * 16 + i];
    a += __shfl_down(a, 4, 8);
    a += __shfl_down(a, 2, 8);
    a += __shfl_down(a, 1, 8);
    if (seg == 0) out[r0 + node] = a + f2b[0];
}

// ---------------- fp32 linear for K=11 (first embed only), packs output ----
template<int K, bool RELU>
__global__ __launch_bounds__(128) void lin_kernel(
    const float* __restrict__ X, const float* __restrict__ W,
    const float* __restrict__ b, uint* __restrict__ out, int n_rows)
{
    constexpr int ROWS = 8;
    __shared__ float xs[ROWS * K];
    const int m  = threadIdx.x;
    const int r0 = blockIdx.x * ROWS;
    for (int i = threadIdx.x; i < ROWS * K; i += 128) {
        int r = i / K, k = i - r * K;
        int row = r0 + r;
        xs[i] = (row < n_rows) ? X[(size_t)row * K + k] : 0.f;
    }
    __syncthreads();
    float acc[ROWS] = {};
    const float* Wm = W + (size_t)m * K;
    for (int k = 0; k < K; ++k) {
        float w = Wm[k];
        #pragma unroll
        for (int r = 0; r < ROWS; ++r) acc[r] += xs[r * K + k] * w;
    }
    const float bias = b[m];
    #pragma unroll
    for (int r = 0; r < ROWS; ++r) {
        int row = r0 + r;
        if (row < n_rows) {
            float v = acc[r] + bias;
            if (RELU) v = fmaxf(v, 0.f);
            out[(size_t)row * HID + m] = packsplit(v);
        }
    }
}

// ---------------- weight prep: pack+swizzle c0_w2, c1_w2 -------------------
__global__ __launch_bounds__(256) void wprep_kernel(
    const float* __restrict__ w0, const float* __restrict__ w1,
    uint* __restrict__ wp)
{
    int i = blockIdx.x * 256 + threadIdx.x;
    if (i >= 32768) return;
    const float* src = (i < 16384) ? w0 : w1;
    int off = (i < 16384) ? 0 : 16384;
    int L = i - off;
    int o = L >> 7, k = L & 127;
    wp[off + wswz(o, k)] = packsplit(src[L]);
}

// ---------------- weight fold: Wq = swz(pack(A·B)), bias' = A·b_in + b_out --
__global__ __launch_bounds__(256) void wfold_kernel(
    const float* __restrict__ A, const float* __restrict__ B,
    const float* __restrict__ b_in, const float* __restrict__ b_out,
    uint* __restrict__ outWq, float* __restrict__ outBias)
{
    const int o = blockIdx.x;
    const int k = threadIdx.x;
    const float* Ar = A + o * 128;
    float s = 0.f;
    for (int j = 0; j < 128; ++j) s += Ar[j] * B[j * 256 + k];
    outWq[wswz(o, k)] = packsplit(s);
    if (k == 0) {
        float sb = 0.f;
        for (int j = 0; j < 128; ++j) sb += Ar[j] * b_in[j];
        outBias[o] = sb + b_out[o];
    }
}

// ---------------- CSR build (by dst) ----------------
__global__ __launch_bounds__(256) void hist_kernel(
    const int* __restrict__ dst, int* __restrict__ cnt)
{
    int e = blockIdx.x * 256 + threadIdx.x;
    if (e < NE) atomicAdd(&cnt[dst[e]], 1);
}

__global__ __launch_bounds__(256) void scan1_kernel(
    const int* __restrict__ cnt, int* __restrict__ row_ptr,
    int* __restrict__ partials)
{
    __shared__ int s[256];
    const int t = threadIdx.x;
    const int i = blockIdx.x * 256 + t;
    int v = (i < NN) ? cnt[i] : 0;
    s[t] = v;
    __syncthreads();
    #pragma unroll
    for (int off = 1; off < 256; off <<= 1) {
        int x = (t >= off) ? s[t - off] : 0;
        __syncthreads();
        s[t] += x;
        __syncthreads();
    }
    if (i < NN) row_ptr[i] = s[t] - v;
    if (t == 255) partials[blockIdx.x] = s[255];
}

__global__ __launch_bounds__(256) void scan2_kernel(
    int* __restrict__ partials, int* __restrict__ row_ptr)
{
    __shared__ int s[256];
    const int t = threadIdx.x;
    int v = (t < SCAN_BLK) ? partials[t] : 0;
    s[t] = v;
    __syncthreads();
    #pragma unroll
    for (int off = 1; off < 256; off <<= 1) {
        int x = (t >= off) ? s[t - off] : 0;
        __syncthreads();
        s[t] += x;
        __syncthreads();
    }
    if (t < SCAN_BLK) partials[t] = s[t] - v;
    if (t == 255) row_ptr[NN] = s[255];
}

__global__ __launch_bounds__(256) void scan3_kernel(
    int* __restrict__ row_ptr, const int* __restrict__ partials)
{
    const int i = blockIdx.x * 256 + threadIdx.x;
    if (i < NN) row_ptr[i] += partials[blockIdx.x];
}

__global__ __launch_bounds__(256) void fill_kernel(
    const int* __restrict__ src, const int* __restrict__ dst,
    const int* __restrict__ row_ptr, int* __restrict__ pos,
    int* __restrict__ esrc)
{
    int e = blockIdx.x * 256 + threadIdx.x;
    if (e >= NE) return;
    int d = dst[e];
    int p = row_ptr[d] + atomicAdd(&pos[d], 1);
    esrc[p] = src[e];
}

extern "C" void kernel_launch(void* const* d_in, const int* in_sizes, int n_in,
                              void* d_out, int out_size, void* d_ws, size_t ws_size,
                              hipStream_t stream)
{
    const float* x     = (const float*)d_in[0];
    const int*   eidx  = (const int*)d_in[1];
    const float* c0_w1 = (const float*)d_in[2],  *c0_b1 = (const float*)d_in[3];
    const float* c0_w2 = (const float*)d_in[4],  *c0_b2 = (const float*)d_in[5];
    const float* c0_w3 = (const float*)d_in[6],  *c0_b3 = (const float*)d_in[7];
    const float* c1_w1 = (const float*)d_in[8],  *c1_b1 = (const float*)d_in[9];
    const float* c1_w2 = (const float*)d_in[10], *c1_b2 = (const float*)d_in[11];
    const float* c1_w3 = (const float*)d_in[12], *c1_b3 = (const float*)d_in[13];
    const float* f_w1  = (const float*)d_in[14], *f_b1  = (const float*)d_in[15];
    const float* f_w2  = (const float*)d_in[16], *f_b2  = (const float*)d_in[17];
    const int* src = eidx;
    const int* dst = eidx + NE;
    float* out = (float*)d_out;

    const size_t BUF = (size_t)NN * HID;
    uint* bA = (uint*)d_ws;
    uint* bB = bA + BUF;
    uint* bC = bB + BUF;
    int* row_ptr  = (int*)(bC + BUF);        // NN+1
    int* cnt      = row_ptr + (NN + 1);      // NN (fill cursor)
    int* esrc     = cnt + NN;                // NE
    int* partials = esrc + NE;               // SCAN_BLK
    uint* wp      = (uint*)(partials + SCAN_BLK);

    uint* p_c0w2 = wp + 0;          // 16384
    uint* p_c1w2 = wp + 16384;      // 16384
    uint* p_Wa   = wp + 32768;      // 32768 (c1_w1 · c0_w3)
    uint* p_Wb   = wp + 65536;      // 32768 (f_w1 · c1_w3)
    float* f_ba  = (float*)(wp + 98304);  // 128
    float* f_bb  = f_ba + 128;            // 128

    const int nb8 = (NN + 7) / 8;     // 5000 (K=11 embed)
    const int nbl = (NN + 31) / 32;   // 1250
    const int eb  = (NE + 255) / 256; // 2500

    // ---- weight prep (pack/swizzle + algebraic folds) + CSR build ----
    wprep_kernel<<<128, 256, 0, stream>>>(c0_w2, c1_w2, wp);
    wfold_kernel<<<128, 256, 0, stream>>>(c1_w1, c0_w3, c0_b3, c1_b1, p_Wa, f_ba);
    wfold_kernel<<<128, 256, 0, stream>>>(f_w1, c1_w3, c1_b3, f_b1, p_Wb, f_bb);
    (void)hipMemsetAsync(cnt, 0, NN * sizeof(int), stream);
    hist_kernel<<<eb, 256, 0, stream>>>(dst, cnt);
    scan1_kernel<<<SCAN_BLK, 256, 0, stream>>>(cnt, row_ptr, partials);
    scan2_kernel<<<1, 256, 0, stream>>>(partials, row_ptr);
    scan3_kernel<<<SCAN_BLK, 256, 0, stream>>>(row_ptr, partials);
    (void)hipMemsetAsync(cnt, 0, NN * sizeof(int), stream);
    fill_kernel<<<eb, 256, 0, stream>>>(src, dst, row_ptr, cnt, esrc);

    // ---- conv0 ----
    lin_kernel<11, true><<<nb8, 128, 0, stream>>>(x, c0_w1, c0_b1, bA, NN);       // h0
    fused_gather_lin_kernel<<<nbl, 512, 0, stream>>>(bA, row_ptr, esrc, p_c0w2, c0_b2, bB); // l1_0
    fused_gather_lin_kernel<<<nbl, 512, 0, stream>>>(bB, row_ptr, esrc, p_c0w2, c0_b2, bC); // l2_0
    lin32_kernel<2, true><<<nbl, 256, 0, stream>>>(bB, bC, p_Wa, f_ba, bA);       // h1 (folded)

    // ---- conv1 ----
    fused_gather_lin_kernel<<<nbl, 512, 0, stream>>>(bA, row_ptr, esrc, p_c1w2, c1_b2, bB); // l1_1
    fused_gather_lin_kernel<<<nbl, 512, 0, stream>>>(bB, row_ptr, esrc, p_c1w2, c1_b2, bC); // l2_1
    cat_head_kernel<<<nbl, 256, 0, stream>>>(bB, bC, p_Wb, f_bb, f_w2, f_b2, out); // folded tail
}